// Round 7
// baseline (370.682 us; speedup 1.0000x reference)
//
#include <hip/hip_runtime.h>
#include <hip/hip_bf16.h>
#include <math.h>

// ---------------- problem constants ----------------
#define N_NODES 20000
#define MP      20096      // 157*128, padded row count for GEMM tiles
#define FIN     500
#define KP      512        // FIN padded to mult of 32
#define NBUCK   157        // CSR buckets of 128 dst nodes each (157*128 = 20096)

typedef unsigned short u16;
typedef unsigned char  u8;
typedef __attribute__((ext_vector_type(8))) short   short8;  // 8 bf16
typedef __attribute__((ext_vector_type(2))) unsigned uv2;    // 8 fp8 bytes
typedef __attribute__((ext_vector_type(2))) float   f32x2;
typedef __attribute__((ext_vector_type(4))) float   f32x4;

__device__ __forceinline__ float b2f(u16 u){
  union { unsigned int i; float f; } v; v.i = ((unsigned int)u) << 16; return v.f;
}
__device__ __forceinline__ u16 f2b(float f){
  __hip_bfloat16 h = __float2bfloat16(f);
  return *reinterpret_cast<u16*>(&h);
}
__device__ __forceinline__ float lrelu(float x){ return x >= 0.f ? x : 0.2f * x; }
__device__ __forceinline__ float ldp(const void* p, int i, int bf){
  return bf ? b2f(((const u16*)p)[i]) : ((const float*)p)[i];
}
// fp8 e4m3 (OCP on gfx950) encode/decode via HW converts.
__device__ __forceinline__ u8 f2fp8(float f){
  return (u8)(__builtin_amdgcn_cvt_pk_fp8_f32(f, 0.f, 0, false) & 0xff);
}
template<bool HI>
__device__ __forceinline__ f32x2 fp8pair(unsigned w){
  return __builtin_amdgcn_cvt_pk_f32_fp8((int)w, HI);
}
// async global->LDS, 16B per lane; LDS dest = wave-uniform base + lane*16
__device__ __forceinline__ void gll16(const u16* g, u16* l){
  __builtin_amdgcn_global_load_lds(
      (const __attribute__((address_space(1))) unsigned int*)g,
      (__attribute__((address_space(3))) unsigned int*)l, 16, 0, 0);
}
// barrier that makes LDS writes visible WITHOUT draining vmcnt (lets a pending
// global atomic stay in flight across the barrier — m201/HK raw-barrier pattern)
__device__ __forceinline__ void barrier_lgkm(){
  asm volatile("s_waitcnt lgkmcnt(0)" ::: "memory");
  __builtin_amdgcn_s_barrier();
  asm volatile("" ::: "memory");
}
// fast tanh via exp: tanh(x) = 1 - 2/(e^{2x}+1); exact saturation at extremes
__device__ __forceinline__ float ftanh(float x){
  float ex = __expf(2.f * x);
  return 1.f - 2.f / (ex + 1.f);
}

// ---------------- dtype detect: 1 = bf16 inputs, 0 = fp32 inputs ----------------
__global__ __launch_bounds__(1024) void detect_dtype_kernel(const unsigned int* __restrict__ xw, int nwords,
                                                            int* __restrict__ flag){
  __shared__ int cnt;
  if (threadIdx.x == 0) cnt = 0;
  __syncthreads();
  int c = 0;
  for (int i = threadIdx.x; i < nwords; i += 1024){
    unsigned e = (xw[i] >> 7) & 0xFF;       // bf16-exponent field of the LOW half-word
    if (e >= 0x70 && e <= 0x8F) c++;        // ~100% if bf16 N(0,1), ~12.5% if fp32 mantissa bits
  }
  atomicAdd(&cnt, c);
  __syncthreads();
  if (threadIdx.x == 0) *flag = (cnt * 2 > nwords) ? 1 : 0;
}

// ---------------- fused prep: y=0 pad_x, y=1 weight transposes, y=2 bucket scatter ---
#define CHA 8192
#define PB  1024
__global__ __launch_bounds__(PB) void prep_kernel(
    const void* __restrict__ x, u16* __restrict__ xp,
    const void* Wb0, const void* Wb1, const void* Wb2,
    const void* Ws0, const void* Ws1, const void* Ws2,
    u16* ob0, u16* ob1, u16* ob2, u16* os0, u16* os1, u16* os2,
    const int* s0, const int* s1, const int* s2,
    const int* d0, const int* d1, const int* d2,
    int E0, int E1, int E2, int S0, int S1, int S2, int EB,
    int* __restrict__ bucketCur, unsigned* p0, unsigned* p1, unsigned* p2,
    const int* __restrict__ flag){
  __shared__ int hb[NBUCK];
  __shared__ int loff[NBUCK];
  __shared__ int hbase[NBUCK];
  __shared__ unsigned shp[CHA];     // staged pairs (32KB)
  __shared__ u8 shb[CHA];           // staged bucket ids (8KB)
  __shared__ u16 tile[64][65];      // transpose tile (padded: ~2-way banks)
  int bf = *flag;
  int tid = threadIdx.x;
  if (blockIdx.y == 0){
    // ---- pad x -> [MP][KP] bf16 ----
    int t = blockIdx.x * PB + tid;
    if (t >= MP * 64) return;
    int row = t >> 6;
    int j0  = (t & 63) * 8;
    short8 v = {0,0,0,0,0,0,0,0};
    if (row < N_NODES){
      if (j0 + 8 <= FIN){
        if (bf){
          const ushort4* xr = (const ushort4*)((const u16*)x + (size_t)row * FIN + j0);
          ushort4 a = xr[0], b = xr[1];
          v[0]=(short)a.x; v[1]=(short)a.y; v[2]=(short)a.z; v[3]=(short)a.w;
          v[4]=(short)b.x; v[5]=(short)b.y; v[6]=(short)b.z; v[7]=(short)b.w;
        } else {
          const float4* xr = (const float4*)((const float*)x + (size_t)row * FIN + j0);
          float4 a = xr[0], b = xr[1];
          v[0]=(short)f2b(a.x); v[1]=(short)f2b(a.y); v[2]=(short)f2b(a.z); v[3]=(short)f2b(a.w);
          v[4]=(short)f2b(b.x); v[5]=(short)f2b(b.y); v[6]=(short)f2b(b.z); v[7]=(short)f2b(b.w);
        }
      } else {
#pragma unroll
        for (int j = 0; j < 8; ++j){
          int k = j0 + j;
          u16 val = 0;
          if (k < FIN)
            val = bf ? ((const u16*)x)[(size_t)row * FIN + k]
                     : f2b(((const float*)x)[(size_t)row * FIN + k]);
          v[j] = (short)val;
        }
      }
    }
    *(short8*)(xp + (size_t)row * KP + j0) = v;
  } else if (blockIdx.y == 1){
    // ---- LDS-tiled coalesced weight transposes ----
    int xb = blockIdx.x;
    if (xb >= 96 + 3) return;
    int tx = tid & 63, tyb = tid >> 6;        // tyb 0..15
    const void* Wsrc; u16* O; int SRCW, SRCH, DSTW, kt, nt;
    if (xb < 96){
      int which = xb >> 5, tl = xb & 31;      // 32 tiles per big weight
      nt = (tl & 3) << 6; kt = (tl >> 2) << 6;
      Wsrc = which == 0 ? Wb0 : (which == 1 ? Wb1 : Wb2);
      O    = which == 0 ? ob0 : (which == 1 ? ob1 : ob2);
      SRCW = 256; SRCH = FIN; DSTW = KP;
    } else {
      int which = xb - 96;
      nt = 0; kt = 0;
      Wsrc = which == 0 ? Ws0 : (which == 1 ? Ws1 : Ws2);
      O    = which == 0 ? os0 : (which == 1 ? os1 : os2);
      SRCW = 64; SRCH = 64; DSTW = 64;
    }
#pragma unroll
    for (int r = 0; r < 4; ++r){
      int kl = tyb + r * 16;
      int k = kt + kl, n = nt + tx;           // lanes walk n -> coalesced read
      u16 vv = 0;
      if (k < SRCH)
        vv = bf ? ((const u16*)Wsrc)[(size_t)k * SRCW + n]
                : f2b(((const float*)Wsrc)[(size_t)k * SRCW + n]);
      tile[kl][tx] = vv;
    }
    __syncthreads();
#pragma unroll
    for (int r = 0; r < 4; ++r){
      int nl = tyb + r * 16;                  // lanes walk k -> coalesced write
      O[(size_t)(nt + nl) * DSTW + kt + tx] = tile[tx][nl];
    }
  } else {
    // ---- bucket scatter with LDS compaction ----
    int sblk = blockIdx.x;
    if (sblk >= 3 * EB) return;
    int g = sblk / EB;
    const int* src = g == 0 ? s0 : (g == 1 ? s1 : s2);
    const int* dst = g == 0 ? d0 : (g == 1 ? d1 : d2);
    unsigned* pairs = g == 0 ? p0 : (g == 1 ? p1 : p2);
    int E = g == 0 ? E0 : (g == 1 ? E1 : E2);
    int S = g == 0 ? S0 : (g == 1 ? S1 : S2);
    int base = (sblk % EB) * CHA;
    if (base >= E) return;
    if (tid < NBUCK) hb[tid] = 0;
    __syncthreads();
    constexpr int EPT = CHA / PB;   // 8 edges/thread
    int rk[EPT]; unsigned pr[EPT]; int bk[EPT]; bool vl[EPT];
#pragma unroll
    for (int i = 0; i < EPT; ++i){
      int e = base + i * PB + tid;
      vl[i] = e < E;
      bk[i] = 0; rk[i] = 0; pr[i] = 0;
      if (vl[i]){
        int dd = dst[e], ss = src[e];
        bk[i] = dd >> 7;
        pr[i] = ((unsigned)ss << 7) | (unsigned)(dd & 127);
        rk[i] = atomicAdd(&hb[bk[i]], 1);
      }
    }
    __syncthreads();
    // issue contended global atomic NOW; consume after staging (overlap)
    int ret = 0;
    if (tid < NBUCK) ret = atomicAdd(&bucketCur[g * NBUCK + tid], hb[tid]);
    if (tid == 0){
      int run = 0;
      for (int k = 0; k < NBUCK; ++k){ loff[k] = run; run += hb[k]; }
    }
    barrier_lgkm();                 // loff visible; bucketCur atomic still in flight
#pragma unroll
    for (int i = 0; i < EPT; ++i)
      if (vl[i]){
        int j = loff[bk[i]] + rk[i];
        shp[j] = pr[i];
        shb[j] = (u8)bk[i];
      }
    if (tid < NBUCK) hbase[tid] = ret;   // vmcnt wait lands here, after staging
    __syncthreads();
    int nb = E - base; if (nb > CHA) nb = CHA;
    // contiguous per-bucket runs -> coalesced segment writes
    for (int j = tid; j < nb; j += PB){
      int b = shb[j];
      int pos = hbase[b] + (j - loff[b]);
      if (pos < S)   // statistical impossibility (>20 sigma), memory-safety clamp
        pairs[(size_t)b * S + pos] = shp[j];
    }
  }
}

// ---------------- big GEMM + fused es/ed + FUSED csr-finalize ------------------------
// z=0: GEMM with XCD-locality remap (supergroups of 48 = 8 m-tiles x 6 (n,g)).
// z=1: csr_finalize (independent; hides under the GEMM).
__global__ __launch_bounds__(256) void gemm_big_kernel(const u16* __restrict__ A,
    const u16* B0, const u16* B1, const u16* B2,
    u8* C0, u8* C1, u8* C2,
    const void* as0, const void* as1, const void* as2,
    const void* ad0, const void* ad1, const void* ad2,
    float* __restrict__ esB, float* __restrict__ edB,
    const int* __restrict__ flag, int M,
    const unsigned* p0, const unsigned* p1, const unsigned* p2,
    int S0, int S1, int S2, const int* __restrict__ bucketCur,
    int* e0, int* e1, int* e2, int2* __restrict__ metaB){
  __shared__ alignas(16) u16 As[128 * 64];
  __shared__ alignas(16) u16 Bs[128 * 64];
  __shared__ int ccnt[128];
  __shared__ int cloff[128];
  __shared__ int ccur[128];
  int t = threadIdx.x;
  if (blockIdx.z == 1){
    // ---- csr finalize: per-bucket counting sort -> meta{start,deg} + esrc ----
    int bxc = blockIdx.x;
    if (bxc >= 3 * NBUCK) return;
    int g = bxc / NBUCK, b = bxc - g * NBUCK;
    const unsigned* pairs = g == 0 ? p0 : (g == 1 ? p1 : p2);
    int* esrc = g == 0 ? e0 : (g == 1 ? e1 : e2);
    int S = g == 0 ? S0 : (g == 1 ? S1 : S2);
    int2* meta = metaB + (size_t)g * MP;
    int nb = bucketCur[g * NBUCK + b];
    if (nb > S) nb = S;
    const unsigned* pb = pairs + (size_t)b * S;
    int* eb = esrc + (size_t)b * S;
    if (t < 128) ccnt[t] = 0;
    __syncthreads();
    for (int i = t; i < nb; i += 256)
      atomicAdd(&ccnt[pb[i] & 127], 1);
    __syncthreads();
    if (t == 0){
      int run = 0;
      for (int k = 0; k < 128; ++k){ cloff[k] = run; run += ccnt[k]; }
    }
    __syncthreads();
    if (t < 128){
      ccur[t] = cloff[t];
      int d = b * 128 + t;
      if (d < N_NODES){
        int2 m; m.x = b * S + cloff[t]; m.y = ccnt[t];
        meta[d] = m;
      }
    }
    __syncthreads();
    for (int i = t; i < nb; i += 256){
      unsigned u = pb[i];
      int slot = atomicAdd(&ccur[u & 127], 1);
      eb[slot] = (int)(u >> 7);
    }
    return;
  }
  // ---- GEMM with XCD-locality remap: supergroup of 48 = 8 m-tiles x 6 (n,g) ----
  int bx = blockIdx.x;
  int grp = bx / 48, j = bx - grp * 48;
  int ng = j >> 3, sub = j & 7;           // ng 0..5, sub 0..7
  int mt = grp * 8 + sub;
  if (mt >= MP / 128) return;             // null blocks in last partial supergroup
  int g  = ng >> 1;                       // graph 0..2
  int n0 = (ng & 1) * 128;
  int m0 = mt * 128;
  const u16* BT = g == 0 ? B0 : (g == 1 ? B1 : B2);
  u8* C = g == 0 ? C0 : (g == 1 ? C1 : C2);
  const void* as_ = g == 0 ? as0 : (g == 1 ? as1 : as2);
  const void* ad_ = g == 0 ? ad0 : (g == 1 ? ad1 : ad2);
  float* es = esB + (size_t)g * N_NODES * 4;
  float* ed = edB + (size_t)g * N_NODES * 4;
  const int K = KP, Nn = 256;
  int lane = t & 63, w = t >> 6;
  int mw = (w >> 1) * 64, nw = (w & 1) * 64;
  f32x4 acc[4][4] = {};
  for (int k0 = 0; k0 < K; k0 += 64){
    __syncthreads();
#pragma unroll
    for (int i = 0; i < 4; ++i){
      int c = i * 256 + w * 64 + lane;   // chunk id 0..1023, 16B each
      int row = c >> 3, slot = c & 7;
      int kk = ((slot ^ (row & 7))) * 8; // source-side XOR swizzle
      gll16(A  + (size_t)(m0 + row) * K + k0 + kk, As + (size_t)(i * 256 + w * 64) * 8);
      gll16(BT + (size_t)(n0 + row) * K + k0 + kk, Bs + (size_t)(i * 256 + w * 64) * 8);
    }
    __syncthreads();
#pragma unroll
    for (int ks = 0; ks < 2; ++ks){
      short8 af[4], bfr[4];
#pragma unroll
      for (int mi = 0; mi < 4; ++mi){
        int row = mw + mi * 16 + (lane & 15);
        int sl = (ks * 4 + (lane >> 4)) ^ (row & 7);
        af[mi] = *(const short8*)(As + (size_t)row * 64 + sl * 8);
      }
#pragma unroll
      for (int ni = 0; ni < 4; ++ni){
        int row = nw + ni * 16 + (lane & 15);
        int sl = (ks * 4 + (lane >> 4)) ^ (row & 7);
        bfr[ni] = *(const short8*)(Bs + (size_t)row * 64 + sl * 8);
      }
#pragma unroll
      for (int mi = 0; mi < 4; ++mi)
#pragma unroll
        for (int ni = 0; ni < 4; ++ni)
          acc[mi][ni] = __builtin_amdgcn_mfma_f32_16x16x32_bf16(af[mi], bfr[ni], acc[mi][ni], 0, 0, 0);
    }
  }
  int bf = *flag;
#pragma unroll
  for (int mi = 0; mi < 4; ++mi)
#pragma unroll
    for (int ni = 0; ni < 4; ++ni)
#pragma unroll
      for (int r = 0; r < 4; ++r){
        int row = m0 + mw + mi * 16 + (lane >> 4) * 4 + r;
        int col = n0 + nw + ni * 16 + (lane & 15);
        if (row < M) C[(size_t)row * Nn + col] = f2fp8(acc[mi][ni][r]);
      }
  // fused es/ed: this wave's cols = n0+nw..+63 = exactly one head; plain stores
  {
    int h = (n0 + nw) >> 6;
    float asv[4], adv[4];
#pragma unroll
    for (int ni = 0; ni < 4; ++ni){
      int col = n0 + nw + ni * 16 + (lane & 15);
      asv[ni] = ldp(as_, col, bf);
      adv[ni] = ldp(ad_, col, bf);
    }
#pragma unroll
    for (int mi = 0; mi < 4; ++mi)
#pragma unroll
      for (int r = 0; r < 4; ++r){
        float ps = 0.f, pd2 = 0.f;
#pragma unroll
        for (int ni = 0; ni < 4; ++ni){
          ps  += acc[mi][ni][r] * asv[ni];
          pd2 += acc[mi][ni][r] * adv[ni];
        }
#pragma unroll
        for (int m2 = 1; m2 < 16; m2 <<= 1){
          ps  += __shfl_xor(ps, m2);
          pd2 += __shfl_xor(pd2, m2);
        }
        int row = m0 + mw + mi * 16 + (lane >> 4) * 4 + r;
        if ((lane & 15) == 0 && row < M){
          es[(size_t)row * 4 + h] = ps;
          ed[(size_t)row * 4 + h] = pd2;
        }
      }
  }
}

// ---------------- small GEMM batched + fused es/ed (XOR-swizzled LDS) ----------------
__global__ __launch_bounds__(256) void gemm_small_kernel(
    const u16* A0, const u16* A1, const u16* A2,
    const u16* B0, const u16* B1, const u16* B2,
    u8* C0, u8* C1, u8* C2,
    const void* as0, const void* as1, const void* as2,
    const void* ad0, const void* ad1, const void* ad2,
    float* __restrict__ esB, float* __restrict__ edB,
    const int* __restrict__ flag, int M){
  int g = blockIdx.y;
  const u16* A  = g == 0 ? A0 : (g == 1 ? A1 : A2);
  const u16* BT = g == 0 ? B0 : (g == 1 ? B1 : B2);
  u8* C = g == 0 ? C0 : (g == 1 ? C1 : C2);
  const void* as_ = g == 0 ? as0 : (g == 1 ? as1 : as2);
  const void* ad_ = g == 0 ? ad0 : (g == 1 ? ad1 : ad2);
  float* es = esB + (size_t)g * N_NODES * 4;
  float* ed = edB + (size_t)g * N_NODES * 4;
  __shared__ alignas(16) u16 As[64 * 64];
  __shared__ alignas(16) u16 Bs[64 * 64];
  int t = threadIdx.x, lane = t & 63, w = t >> 6;
  int m0 = blockIdx.x * 64;
#pragma unroll
  for (int i = 0; i < 2; ++i){
    int c = i * 256 + w * 64 + lane;     // 512 chunks of 16B = 8KB tile
    int row = c >> 3, slot = c & 7;
    int kk = ((slot ^ (row & 7))) * 8;   // source-side XOR swizzle
    gll16(A  + (size_t)(m0 + row) * 64 + kk, As + (size_t)(i * 256 + w * 64) * 8);
    gll16(BT + (size_t)row * 64 + kk,        Bs + (size_t)(i * 256 + w * 64) * 8);
  }
  __syncthreads();
  f32x4 acc[4] = {};
  int mw = w * 16;
#pragma unroll
  for (int ks = 0; ks < 2; ++ks){
    int rowa = mw + (lane & 15);
    int sla = (ks * 4 + (lane >> 4)) ^ (rowa & 7);
    short8 af = *(const short8*)(As + (size_t)rowa * 64 + sla * 8);
#pragma unroll
    for (int ni = 0; ni < 4; ++ni){
      int rowb = ni * 16 + (lane & 15);
      int slb = (ks * 4 + (lane >> 4)) ^ (rowb & 7);
      short8 bv = *(const short8*)(Bs + (size_t)rowb * 64 + slb * 8);
      acc[ni] = __builtin_amdgcn_mfma_f32_16x16x32_bf16(af, bv, acc[ni], 0, 0, 0);
    }
  }
  int bf = *flag;
#pragma unroll
  for (int ni = 0; ni < 4; ++ni)
#pragma unroll
    for (int r = 0; r < 4; ++r){
      int row = m0 + mw + (lane >> 4) * 4 + r;
      int col = ni * 16 + (lane & 15);
      if (row < M) C[(size_t)row * 64 + col] = f2fp8(acc[ni][r]);
    }
  // fused es/ed: head = ni (16 cols per head, all 4 heads in-block) -> direct store
  {
    float asv[4], adv[4];
#pragma unroll
    for (int ni = 0; ni < 4; ++ni){
      int col = ni * 16 + (lane & 15);
      asv[ni] = ldp(as_, col, bf);
      adv[ni] = ldp(ad_, col, bf);
    }
#pragma unroll
    for (int r = 0; r < 4; ++r){
      float ps[4], pd2[4];
#pragma unroll
      for (int ni = 0; ni < 4; ++ni){ ps[ni] = acc[ni][r] * asv[ni]; pd2[ni] = acc[ni][r] * adv[ni]; }
#pragma unroll
      for (int m2 = 1; m2 < 16; m2 <<= 1)
#pragma unroll
        for (int ni = 0; ni < 4; ++ni){
          ps[ni]  += __shfl_xor(ps[ni], m2);
          pd2[ni] += __shfl_xor(pd2[ni], m2);
        }
      int row = m0 + mw + (lane >> 4) * 4 + r;
      if ((lane & 15) == 0 && row < M){
#pragma unroll
        for (int ni = 0; ni < 4; ++ni){
          es[(size_t)row * 4 + ni] = ps[ni];
          ed[(size_t)row * 4 + ni] = pd2[ni];
        }
      }
    }
  }
}

// ---------------- GAT aggregate from fp8 z (bulk-gathered ep/p, r0 compute body) -----
// Theory: kernel is vector-memory REQUEST-throughput bound (each 64-lane gather
// occupies the TA pipe regardless of width). Cut load-instructions ~3x:
//  - ep: ONE coalesced 64-lane load per BULK(60/64)-edge block; slot ids via bpermute.
//  - p = exp(lrelu(es+ed)): computed ONCE per (edge,head) in a bulk phase
//    (lane=(e<<2)|h, 4 es-gather instrs per block) and distributed via bpermute.
// Inner loop per slot: 1 z-load + 2 bpermute + cvt/fma. Static p-reg indices via
// fully-unrolled tb/i loops (slot blocks never cross 16-slot register boundaries).
template<int DT, bool RELU, bool BF16OUT, int PIPE>   // DT = channels = bytes/row
__global__ __launch_bounds__(256) void gat_agg5_kernel(
    const u8* z0, const u8* z1, const u8* z2,
    const float* __restrict__ esB, const float* __restrict__ edB,
    const int2* __restrict__ metaB,
    const int* e0p, const int* e1p, const int* e2p,
    const void* b0, const void* b1, const void* b2,
    void* o0, void* o1, void* o2,
    const int* __restrict__ flag){
  int g = blockIdx.y;
  const u8* z = g == 0 ? z0 : (g == 1 ? z1 : z2);
  const int* esrc = g == 0 ? e0p : (g == 1 ? e1p : e2p);
  const void* bias = g == 0 ? b0 : (g == 1 ? b1 : b2);
  void* out = g == 0 ? o0 : (g == 1 ? o1 : o2);
  const float* es = esB + (size_t)g * N_NODES * 4;
  const float* ed = edB + (size_t)g * N_NODES * 4;
  const int2* meta = metaB + (size_t)g * MP;
  int bf = *flag;

  int d = (blockIdx.x * 256 + threadIdx.x) >> 6;
  int lane = threadIdx.x & 63;
  if (d >= N_NODES) return;
  constexpr int LPG = DT / 8;        // lanes per edge-group: 32 (DT256) / 8 (DT64)
  constexpr int G   = 64 / LPG;      // groups: 2 / 8
  constexpr int HD  = DT / 4;        // channels per head == output width: 64 / 16
  constexpr int CHK = PIPE * G;      // slots per inner chunk: 12 / 32
  constexpr int TBS = 64 / CHK;      // chunks per bulk block: 5 / 2
  constexpr int BULK = TBS * CHK;    // edges per bulk block: 60 / 64
  int grp = lane / LPG;
  int li  = lane % LPG;
  int c0  = li * 8;                  // byte offset of this lane's 8 channels
  int h   = c0 / HD;
  int gh4 = (grp << 2) | h;          // bpermute lane offset within a 16-slot block
  int ebk = lane >> 2;               // bulk phase: edge-within-16
  int hbk = lane & 3;                // bulk phase: head

  int2 md = meta[d];
  int deg = md.y;
  const int* ep = esrc + md.x;
  const u8* zl = z + c0;
  float edhb = ed[(unsigned)d * 4 + hbk];   // bulk-lane's head bias

  float acc[8] = {0,0,0,0,0,0,0,0};
  float sacc = 0.f;

  for (int base = 0; base < deg; base += BULK){
    int nloc = deg - base; if (nloc > BULK) nloc = BULK;
    // bulk 1: edge ids, one coalesced load
    int eid = 0;
    if (lane < nloc) eid = ep[base + lane];
    // bulk 2: p per (edge,head); 16 edges x 4 heads per register
    float pb[4];
#pragma unroll
    for (int j = 0; j < 4; ++j){
      pb[j] = 0.f;
      if (j * 16 < nloc){                       // wave-uniform guard
        int sl = j * 16 + ebk;
        int pe = __shfl(eid, sl);
        float ev = es[(unsigned)pe * 4 + hbk];  // gather (dead lanes hit es[0..3])
        float pv = __expf(lrelu(ev + edhb));
        pb[j] = (sl < nloc) ? pv : 0.f;
      }
    }
    // inner: z-gather + weighted accumulate (r0 body); static pb indices
#pragma unroll
    for (int tb = 0; tb < TBS; ++tb){
      if (tb * CHK >= nloc) break;              // wave-uniform
      int s_[PIPE]; float q_[PIPE]; uv2 v_[PIPE];
#pragma unroll
      for (int i = 0; i < PIPE; ++i){
        int sb = tb * CHK + i * G;              // compile-const after unroll
        s_[i] = __shfl(eid, sb + grp);          // dead slots -> eid 0 -> z[0]
        q_[i] = __shfl(pb[sb >> 4], ((sb & 15) << 2) + gh4);  // dead -> 0
      }
#pragma unroll
      for (int i = 0; i < PIPE; ++i) v_[i] = *(const uv2*)(zl + (unsigned)s_[i] * DT);
#pragma unroll
      for (int i = 0; i < PIPE; ++i){
        float p = q_[i];
        sacc += p;
        f32x2 a0 = fp8pair<false>(v_[i][0]), a1 = fp8pair<true>(v_[i][0]);
        f32x2 a2 = fp8pair<false>(v_[i][1]), a3 = fp8pair<true>(v_[i][1]);
        acc[0] = fmaf(p, a0.x, acc[0]); acc[1] = fmaf(p, a0.y, acc[1]);
        acc[2] = fmaf(p, a1.x, acc[2]); acc[3] = fmaf(p, a1.y, acc[3]);
        acc[4] = fmaf(p, a2.x, acc[4]); acc[5] = fmaf(p, a2.y, acc[5]);
        acc[6] = fmaf(p, a3.x, acc[6]); acc[7] = fmaf(p, a3.y, acc[7]);
      }
    }
  }

  // sum over edge-groups (lanes with same li share channel+head)
#pragma unroll
  for (int m = LPG; m < 64; m <<= 1){
    sacc += __shfl_xor(sacc, m);
#pragma unroll
    for (int j = 0; j < 8; ++j) acc[j] += __shfl_xor(acc[j], m);
  }
  float inv = 1.f / (sacc + 1e-16f);
  float v8[8];
#pragma unroll
  for (int j = 0; j < 8; ++j) v8[j] = acc[j] * inv;
  // mean over heads: lanes li, li^(HD/8), ... hold same dd different heads
#pragma unroll
  for (int m = HD / 8; m < LPG; m <<= 1)
#pragma unroll
    for (int j = 0; j < 8; ++j) v8[j] += __shfl_xor(v8[j], m);

  if (lane < HD / 8){
    if constexpr (BF16OUT){
      short8 ov;
#pragma unroll
      for (int j = 0; j < 8; ++j){
        float o = v8[j] * 0.25f + ldp(bias, lane * 8 + j, bf);
        if (RELU) o = fmaxf(o, 0.f);
        ov[j] = (short)f2b(o);
      }
      *(short8*)((u16*)out + (size_t)d * HD + lane * 8) = ov;
    } else {
      float o[8];
#pragma unroll
      for (int j = 0; j < 8; ++j){
        o[j] = v8[j] * 0.25f + ldp(bias, lane * 8 + j, bf);
        if (RELU) o[j] = fmaxf(o[j], 0.f);
      }
      float* op = (float*)out + (size_t)d * HD + lane * 8;
      *(float4*)op = make_float4(o[0], o[1], o[2], o[3]);
      *(float4*)(op + 4) = make_float4(o[4], o[5], o[6], o[7]);
    }
  }
}

// ---------------- final: branch attention + combine + log_softmax ----------------
__global__ __launch_bounds__(256) void final_combine_kernel(
    const float* __restrict__ h1, const float* __restrict__ h2, const float* __restrict__ h3,
    const void* l1w, const void* l1b, const void* l2w, const void* l2b,
    const void* l3w, const void* l3b, const void* aggw,
    void* __restrict__ outv, int n, const int* __restrict__ flag){
  __shared__ float Lw[3][16][16];
  __shared__ float Lb[3][16];
  __shared__ float Ag[16];
  int t = threadIdx.x;
  int bf = *flag;
  {
    const void* ws[3] = { l1w, l2w, l3w };
    for (int g = 0; g < 3; ++g) Lw[g][t / 16][t % 16] = ldp(ws[g], t, bf);
    if (t < 16){
      Lb[0][t] = ldp(l1b, t, bf); Lb[1][t] = ldp(l2b, t, bf); Lb[2][t] = ldp(l3b, t, bf);
      Ag[t] = ldp(aggw, t, bf);
    }
  }
  __syncthreads();
  int node = blockIdx.x * 256 + t;
  if (node >= n) return;
  const float* hp[3] = { h1, h2, h3 };
  float hv[3][16];
  float a[3];
  for (int g = 0; g < 3; ++g){
    const float4* h4 = (const float4*)(hp[g] + (size_t)node * 16);
#pragma unroll
    for (int q = 0; q < 4; ++q){
      float4 f = h4[q];
      hv[g][q * 4 + 0] = f.x; hv[g][q * 4 + 1] = f.y;
      hv[g][q * 4 + 2] = f.z; hv[g][q * 4 + 3] = f.w;
    }
    float dot = 0.f;
#pragma unroll
    for (int j = 0; j < 16; ++j){
      float acc2 = Lb[g][j];
#pragma unroll
      for (int i = 0; i < 16; ++i) acc2 += hv[g][i] * Lw[g][i][j];
      dot += ftanh(acc2) * Ag[j];
    }
    a[g] = dot;
  }
  float am = fmaxf(a[0], fmaxf(a[1], a[2]));
  float e0 = __expf(a[0] - am), e1 = __expf(a[1] - am), e2 = __expf(a[2] - am);
  float einv = 1.f / (e0 + e1 + e2);
  float w0 = e0 * einv, w1 = e1 * einv, w2 = e2 * einv;
  float hh[16];
  float hmax = -INFINITY;
#pragma unroll
  for (int i = 0; i < 16; ++i){
    hh[i] = w0 * hv[0][i] + w1 * hv[1][i] + w2 * hv[2][i];
    hmax = fmaxf(hmax, hh[i]);
  }
  float se = 0.f;
#pragma unroll
  for (int i = 0; i < 16; ++i) se += __expf(hh[i] - hmax);
  float ls = hmax + logf(se);
#pragma unroll
  for (int i = 0; i < 16; ++i){
    float o = hh[i] - ls;
    if (bf) ((__hip_bfloat16*)outv)[(size_t)node * 16 + i] = __float2bfloat16(o);
    else    ((float*)outv)[(size_t)node * 16 + i] = o;
  }
}

// ---------------- host ----------------
extern "C" void kernel_launch(void* const* d_in, const int* in_sizes, int n_in,
                              void* d_out, int out_size, void* d_ws, size_t ws_size,
                              hipStream_t stream){
  const void* x = d_in[0];
  const int* ei[3] = { (const int*)d_in[1], (const int*)d_in[2], (const int*)d_in[3] };
  int E[3] = { in_sizes[1] / 2, in_sizes[2] / 2, in_sizes[3] / 2 };
  int Emax = E[0] > E[1] ? E[0] : E[1]; if (E[2] > Emax) Emax = E[2];
  int EB = (Emax + CHA - 1) / CHA;
  int S[3];
  for (int g = 0; g < 3; ++g){
    long s = ((long)E[g] * 27 / 20) / NBUCK + 64;
    s &= ~63L; if (s > 8192) s = 8192;
    S[g] = (int)s;
  }
  const void *W[6], *as_[6], *ad_[6], *bb[6];
  for (int j = 0; j < 6; ++j){
    W[j]   = d_in[4 + 4 * j];
    as_[j] = d_in[5 + 4 * j];
    ad_[j] = d_in[6 + 4 * j];
    bb[j]  = d_in[7 + 4 * j];
  }
  const void* l1w = d_in[28]; const void* l1b = d_in[29];
  const void* l2w = d_in[30]; const void* l2b = d_in[31];
  const void* l3w = d_in[32]; const void* l3b = d_in[33];
  const void* agg = d_in[34];

  // ---- workspace carve ----
  char* p = (char*)d_ws;
  auto alloc = [&](size_t bytes) -> void* {
    void* r = (void*)p;
    p += (bytes + 255) & ~(size_t)255;
    return r;
  };
  int* dflag = (int*)alloc(256);
  u16* xp = (u16*)alloc((size_t)MP * KP * 2);           // padded x, bf16 (20.6 MB)
  u16* hmid[3]; for (int g = 0; g < 3; ++g) hmid[g] = xp + (size_t)g * MP * 64;       // alias
  u16* wtb[3]; for (int g = 0; g < 3; ++g) wtb[g] = (u16*)alloc((size_t)256 * KP * 2);
  u16* wts[3]; for (int g = 0; g < 3; ++g) wts[g] = (u16*)alloc((size_t)64 * 64 * 2);
  u8* zf[3];   for (int g = 0; g < 3; ++g) zf[g]  = (u8*)alloc((size_t)N_NODES * 256 + 256);
  float* hbr[3]; for (int g = 0; g < 3; ++g) hbr[g] = (float*)alloc((size_t)N_NODES * 16 * 4);
  float* esB = (float*)alloc((size_t)3 * N_NODES * 4 * 4);
  float* edB = (float*)alloc((size_t)3 * N_NODES * 4 * 4);
  int* bucketCur = (int*)alloc((size_t)3 * NBUCK * 4);
  int2* metaB    = (int2*)alloc((size_t)3 * MP * 8);
  int* esrc[3];
  for (int g = 0; g < 3; ++g) esrc[g] = (int*)alloc(((size_t)NBUCK * S[g] + 256) * 4);
  unsigned* pairs[3];
  for (int g = 0; g < 3; ++g) pairs[g] = (unsigned*)alloc(((size_t)NBUCK * S[g] + 256) * 4);

  const int* s0 = ei[0];          const int* s1 = ei[1];          const int* s2 = ei[2];
  const int* d0 = ei[0] + E[0];   const int* d1 = ei[1] + E[1];   const int* d2 = ei[2] + E[2];

  (void)hipMemsetAsync(bucketCur, 0, (size_t)3 * NBUCK * 4, stream);
  detect_dtype_kernel<<<1, 1024, 0, stream>>>((const unsigned int*)x, 4096, dflag);
  prep_kernel<<<dim3((MP * 64 + PB - 1) / PB, 3), PB, 0, stream>>>(
      x, xp, W[0], W[2], W[4], W[1], W[3], W[5],
      wtb[0], wtb[1], wtb[2], wts[0], wts[1], wts[2],
      s0, s1, s2, d0, d1, d2, E[0], E[1], E[2], S[0], S[1], S[2], EB,
      bucketCur, pairs[0], pairs[1], pairs[2], dflag);

  const int convGrid = (N_NODES + 3) / 4;   // 4 waves/block, wave per dst

  // layer 1 GEMM (z=0, 20 supergroups x 48 blocks) + fused csr finalize (z=1)
  gemm_big_kernel<<<dim3(20 * 48, 1, 2), 256, 0, stream>>>(
      xp, wtb[0], wtb[1], wtb[2], zf[0], zf[1], zf[2],
      as_[0], as_[2], as_[4], ad_[0], ad_[2], ad_[4], esB, edB, dflag, N_NODES,
      pairs[0], pairs[1], pairs[2], S[0], S[1], S[2], bucketCur,
      esrc[0], esrc[1], esrc[2], metaB);
  gat_agg5_kernel<256, true, true, 6><<<dim3(convGrid, 3), 256, 0, stream>>>(
      zf[0], zf[1], zf[2], esB, edB, metaB, esrc[0], esrc[1], esrc[2],
      bb[0], bb[2], bb[4], (void*)hmid[0], (void*)hmid[1], (void*)hmid[2], dflag);

  // layer 2: 64 -> 16, H=4 (DT=64), no relu, fp32 out into hbr
  gemm_small_kernel<<<dim3(MP / 64, 3), 256, 0, stream>>>(
      hmid[0], hmid[1], hmid[2], wts[0], wts[1], wts[2], zf[0], zf[1], zf[2],
      as_[1], as_[3], as_[5], ad_[1], ad_[3], ad_[5], esB, edB, dflag, N_NODES);
  gat_agg5_kernel<64, false, false, 4><<<dim3(convGrid, 3), 256, 0, stream>>>(
      zf[0], zf[1], zf[2], esB, edB, metaB, esrc[0], esrc[1], esrc[2],
      bb[1], bb[3], bb[5], (void*)hbr[0], (void*)hbr[1], (void*)hbr[2], dflag);

  final_combine_kernel<<<(N_NODES + 255) / 256, 256, 0, stream>>>(
      hbr[0], hbr[1], hbr[2], l1w, l1b, l2w, l2b, l3w, l3b, agg,
      d_out, N_NODES, dflag);
}

// Round 8
// 319.721 us; speedup vs baseline: 1.1594x; 1.1594x over previous
//
#include <hip/hip_runtime.h>
#include <hip/hip_bf16.h>
#include <math.h>

// ---------------- problem constants ----------------
#define N_NODES 20000
#define MP      20096      // 157*128, padded row count for GEMM tiles
#define FIN     500
#define KP      512        // FIN padded to mult of 32
#define NBUCK   157        // CSR buckets of 128 dst nodes each (157*128 = 20096)

typedef unsigned short u16;
typedef unsigned char  u8;
typedef __attribute__((ext_vector_type(8))) short   short8;  // 8 bf16
typedef __attribute__((ext_vector_type(2))) unsigned uv2;    // 8 fp8 bytes
typedef __attribute__((ext_vector_type(2))) float   f32x2;
typedef __attribute__((ext_vector_type(4))) float   f32x4;

__device__ __forceinline__ float b2f(u16 u){
  union { unsigned int i; float f; } v; v.i = ((unsigned int)u) << 16; return v.f;
}
__device__ __forceinline__ u16 f2b(float f){
  __hip_bfloat16 h = __float2bfloat16(f);
  return *reinterpret_cast<u16*>(&h);
}
__device__ __forceinline__ float lrelu(float x){ return x >= 0.f ? x : 0.2f * x; }
__device__ __forceinline__ float ldp(const void* p, int i, int bf){
  return bf ? b2f(((const u16*)p)[i]) : ((const float*)p)[i];
}
// fp8 e4m3 (OCP on gfx950) encode/decode via HW converts.
__device__ __forceinline__ u8 f2fp8(float f){
  return (u8)(__builtin_amdgcn_cvt_pk_fp8_f32(f, 0.f, 0, false) & 0xff);
}
template<bool HI>
__device__ __forceinline__ f32x2 fp8pair(unsigned w){
  return __builtin_amdgcn_cvt_pk_f32_fp8((int)w, HI);
}
// async global->LDS, 16B per lane; LDS dest = wave-uniform base + lane*16
__device__ __forceinline__ void gll16(const u16* g, u16* l){
  __builtin_amdgcn_global_load_lds(
      (const __attribute__((address_space(1))) unsigned int*)g,
      (__attribute__((address_space(3))) unsigned int*)l, 16, 0, 0);
}
// barrier that makes LDS writes visible WITHOUT draining vmcnt (lets a pending
// global atomic stay in flight across the barrier — m201/HK raw-barrier pattern)
__device__ __forceinline__ void barrier_lgkm(){
  asm volatile("s_waitcnt lgkmcnt(0)" ::: "memory");
  __builtin_amdgcn_s_barrier();
  asm volatile("" ::: "memory");
}
// fast tanh via exp: tanh(x) = 1 - 2/(e^{2x}+1); exact saturation at extremes
__device__ __forceinline__ float ftanh(float x){
  float ex = __expf(2.f * x);
  return 1.f - 2.f / (ex + 1.f);
}

// ---------------- fused prep: y=0 pad_x, y=1 weight transposes, y=2 bucket scatter ---
// Dtype detect is FOLDED IN: y=0/y=1 blocks re-derive the bf16-vs-fp32 flag from x's
// first 16KB (L2-broadcast after the first block, deterministic across blocks);
// block (0,0) publishes dflag for the downstream kernels. Removes the serialized
// 1-block detect dispatch.
#define CHA 8192
#define PB  1024
__global__ __launch_bounds__(PB) void prep_kernel(
    const void* __restrict__ x, u16* __restrict__ xp,
    const void* Wb0, const void* Wb1, const void* Wb2,
    const void* Ws0, const void* Ws1, const void* Ws2,
    u16* ob0, u16* ob1, u16* ob2, u16* os0, u16* os1, u16* os2,
    const int* s0, const int* s1, const int* s2,
    const int* d0, const int* d1, const int* d2,
    int E0, int E1, int E2, int S0, int S1, int S2, int EB,
    int* __restrict__ bucketCur, unsigned* p0, unsigned* p1, unsigned* p2,
    int* __restrict__ dflag){
  __shared__ int hb[NBUCK];
  __shared__ int loff[NBUCK];
  __shared__ int hbase[NBUCK];
  __shared__ unsigned shp[CHA];     // staged pairs (32KB)
  __shared__ u8 shb[CHA];           // staged bucket ids (8KB)
  __shared__ u16 tile[64][65];      // transpose tile (padded: ~2-way banks)
  __shared__ int dcnt;
  int tid = threadIdx.x;
  int bf = 0;
  if (blockIdx.y != 2){
    // ---- inline dtype detect over x[0:4096 words] (same result in every block) ----
    if (tid == 0) dcnt = 0;
    __syncthreads();
    {
      const unsigned* xw = (const unsigned*)x;
      int c = 0;
#pragma unroll
      for (int i = 0; i < 4; ++i){
        unsigned e = (xw[tid + i * PB] >> 7) & 0xFF;  // bf16-exp field of low half
        if (e >= 0x70 && e <= 0x8F) c++;              // ~100% bf16, ~12.5% fp32
      }
#pragma unroll
      for (int m = 1; m < 64; m <<= 1) c += __shfl_xor(c, m);
      if ((tid & 63) == 0) atomicAdd(&dcnt, c);
    }
    __syncthreads();
    bf = (dcnt * 2 > 4096) ? 1 : 0;
    if (blockIdx.x == 0 && blockIdx.y == 0 && tid == 0) *dflag = bf;
  }
  if (blockIdx.y == 0){
    // ---- pad x -> [MP][KP] bf16 ----
    int t = blockIdx.x * PB + tid;
    if (t >= MP * 64) return;
    int row = t >> 6;
    int j0  = (t & 63) * 8;
    short8 v = {0,0,0,0,0,0,0,0};
    if (row < N_NODES){
      if (j0 + 8 <= FIN){
        if (bf){
          const ushort4* xr = (const ushort4*)((const u16*)x + (size_t)row * FIN + j0);
          ushort4 a = xr[0], b = xr[1];
          v[0]=(short)a.x; v[1]=(short)a.y; v[2]=(short)a.z; v[3]=(short)a.w;
          v[4]=(short)b.x; v[5]=(short)b.y; v[6]=(short)b.z; v[7]=(short)b.w;
        } else {
          const float4* xr = (const float4*)((const float*)x + (size_t)row * FIN + j0);
          float4 a = xr[0], b = xr[1];
          v[0]=(short)f2b(a.x); v[1]=(short)f2b(a.y); v[2]=(short)f2b(a.z); v[3]=(short)f2b(a.w);
          v[4]=(short)f2b(b.x); v[5]=(short)f2b(b.y); v[6]=(short)f2b(b.z); v[7]=(short)f2b(b.w);
        }
      } else {
#pragma unroll
        for (int j = 0; j < 8; ++j){
          int k = j0 + j;
          u16 val = 0;
          if (k < FIN)
            val = bf ? ((const u16*)x)[(size_t)row * FIN + k]
                     : f2b(((const float*)x)[(size_t)row * FIN + k]);
          v[j] = (short)val;
        }
      }
    }
    *(short8*)(xp + (size_t)row * KP + j0) = v;
  } else if (blockIdx.y == 1){
    // ---- LDS-tiled coalesced weight transposes ----
    int xb = blockIdx.x;
    if (xb >= 96 + 3) return;
    int tx = tid & 63, tyb = tid >> 6;        // tyb 0..15
    const void* Wsrc; u16* O; int SRCW, SRCH, DSTW, kt, nt;
    if (xb < 96){
      int which = xb >> 5, tl = xb & 31;      // 32 tiles per big weight
      nt = (tl & 3) << 6; kt = (tl >> 2) << 6;
      Wsrc = which == 0 ? Wb0 : (which == 1 ? Wb1 : Wb2);
      O    = which == 0 ? ob0 : (which == 1 ? ob1 : ob2);
      SRCW = 256; SRCH = FIN; DSTW = KP;
    } else {
      int which = xb - 96;
      nt = 0; kt = 0;
      Wsrc = which == 0 ? Ws0 : (which == 1 ? Ws1 : Ws2);
      O    = which == 0 ? os0 : (which == 1 ? os1 : os2);
      SRCW = 64; SRCH = 64; DSTW = 64;
    }
#pragma unroll
    for (int r = 0; r < 4; ++r){
      int kl = tyb + r * 16;
      int k = kt + kl, n = nt + tx;           // lanes walk n -> coalesced read
      u16 vv = 0;
      if (k < SRCH)
        vv = bf ? ((const u16*)Wsrc)[(size_t)k * SRCW + n]
                : f2b(((const float*)Wsrc)[(size_t)k * SRCW + n]);
      tile[kl][tx] = vv;
    }
    __syncthreads();
#pragma unroll
    for (int r = 0; r < 4; ++r){
      int nl = tyb + r * 16;                  // lanes walk k -> coalesced write
      O[(size_t)(nt + nl) * DSTW + kt + tx] = tile[tx][nl];
    }
  } else {
    // ---- bucket scatter with LDS compaction (no bf needed) ----
    int sblk = blockIdx.x;
    if (sblk >= 3 * EB) return;
    int g = sblk / EB;
    const int* src = g == 0 ? s0 : (g == 1 ? s1 : s2);
    const int* dst = g == 0 ? d0 : (g == 1 ? d1 : d2);
    unsigned* pairs = g == 0 ? p0 : (g == 1 ? p1 : p2);
    int E = g == 0 ? E0 : (g == 1 ? E1 : E2);
    int S = g == 0 ? S0 : (g == 1 ? S1 : S2);
    int base = (sblk % EB) * CHA;
    if (base >= E) return;
    if (tid < NBUCK) hb[tid] = 0;
    __syncthreads();
    constexpr int EPT = CHA / PB;   // 8 edges/thread
    int rk[EPT]; unsigned pr[EPT]; int bk[EPT]; bool vl[EPT];
#pragma unroll
    for (int i = 0; i < EPT; ++i){
      int e = base + i * PB + tid;
      vl[i] = e < E;
      bk[i] = 0; rk[i] = 0; pr[i] = 0;
      if (vl[i]){
        int dd = dst[e], ss = src[e];
        bk[i] = dd >> 7;
        pr[i] = ((unsigned)ss << 7) | (unsigned)(dd & 127);
        rk[i] = atomicAdd(&hb[bk[i]], 1);
      }
    }
    __syncthreads();
    // issue contended global atomic NOW; consume after staging (overlap)
    int ret = 0;
    if (tid < NBUCK) ret = atomicAdd(&bucketCur[g * NBUCK + tid], hb[tid]);
    if (tid == 0){
      int run = 0;
      for (int k = 0; k < NBUCK; ++k){ loff[k] = run; run += hb[k]; }
    }
    barrier_lgkm();                 // loff visible; bucketCur atomic still in flight
#pragma unroll
    for (int i = 0; i < EPT; ++i)
      if (vl[i]){
        int j = loff[bk[i]] + rk[i];
        shp[j] = pr[i];
        shb[j] = (u8)bk[i];
      }
    if (tid < NBUCK) hbase[tid] = ret;   // vmcnt wait lands here, after staging
    __syncthreads();
    int nb = E - base; if (nb > CHA) nb = CHA;
    // contiguous per-bucket runs -> coalesced segment writes
    for (int j = tid; j < nb; j += PB){
      int b = shb[j];
      int pos = hbase[b] + (j - loff[b]);
      if (pos < S)   // statistical impossibility (>20 sigma), memory-safety clamp
        pairs[(size_t)b * S + pos] = shp[j];
    }
  }
}

// ---------------- big GEMM + fused es/ed + FUSED csr-finalize ------------------------
// z=0: GEMM with XCD-locality remap (supergroups of 48 = 8 m-tiles x 6 (n,g)).
// z=1: csr_finalize (independent; hides under the GEMM).
__global__ __launch_bounds__(256) void gemm_big_kernel(const u16* __restrict__ A,
    const u16* B0, const u16* B1, const u16* B2,
    u8* C0, u8* C1, u8* C2,
    const void* as0, const void* as1, const void* as2,
    const void* ad0, const void* ad1, const void* ad2,
    float* __restrict__ esB, float* __restrict__ edB,
    const int* __restrict__ flag, int M,
    const unsigned* p0, const unsigned* p1, const unsigned* p2,
    int S0, int S1, int S2, const int* __restrict__ bucketCur,
    int* e0, int* e1, int* e2, int2* __restrict__ metaB){
  __shared__ alignas(16) u16 As[128 * 64];
  __shared__ alignas(16) u16 Bs[128 * 64];
  __shared__ int ccnt[128];
  __shared__ int cloff[128];
  __shared__ int ccur[128];
  int t = threadIdx.x;
  if (blockIdx.z == 1){
    // ---- csr finalize: per-bucket counting sort -> meta{start,deg} + esrc ----
    int bxc = blockIdx.x;
    if (bxc >= 3 * NBUCK) return;
    int g = bxc / NBUCK, b = bxc - g * NBUCK;
    const unsigned* pairs = g == 0 ? p0 : (g == 1 ? p1 : p2);
    int* esrc = g == 0 ? e0 : (g == 1 ? e1 : e2);
    int S = g == 0 ? S0 : (g == 1 ? S1 : S2);
    int2* meta = metaB + (size_t)g * MP;
    int nb = bucketCur[g * NBUCK + b];
    if (nb > S) nb = S;
    const unsigned* pb = pairs + (size_t)b * S;
    int* eb = esrc + (size_t)b * S;
    if (t < 128) ccnt[t] = 0;
    __syncthreads();
    for (int i = t; i < nb; i += 256)
      atomicAdd(&ccnt[pb[i] & 127], 1);
    __syncthreads();
    if (t == 0){
      int run = 0;
      for (int k = 0; k < 128; ++k){ cloff[k] = run; run += ccnt[k]; }
    }
    __syncthreads();
    if (t < 128){
      ccur[t] = cloff[t];
      int d = b * 128 + t;
      if (d < N_NODES){
        int2 m; m.x = b * S + cloff[t]; m.y = ccnt[t];
        meta[d] = m;
      }
    }
    __syncthreads();
    for (int i = t; i < nb; i += 256){
      unsigned u = pb[i];
      int slot = atomicAdd(&ccur[u & 127], 1);
      eb[slot] = (int)(u >> 7);
    }
    return;
  }
  // ---- GEMM with XCD-locality remap: supergroup of 48 = 8 m-tiles x 6 (n,g) ----
  int bx = blockIdx.x;
  int grp = bx / 48, j = bx - grp * 48;
  int ng = j >> 3, sub = j & 7;           // ng 0..5, sub 0..7
  int mt = grp * 8 + sub;
  if (mt >= MP / 128) return;             // null blocks in last partial supergroup
  int g  = ng >> 1;                       // graph 0..2
  int n0 = (ng & 1) * 128;
  int m0 = mt * 128;
  const u16* BT = g == 0 ? B0 : (g == 1 ? B1 : B2);
  u8* C = g == 0 ? C0 : (g == 1 ? C1 : C2);
  const void* as_ = g == 0 ? as0 : (g == 1 ? as1 : as2);
  const void* ad_ = g == 0 ? ad0 : (g == 1 ? ad1 : ad2);
  float* es = esB + (size_t)g * N_NODES * 4;
  float* ed = edB + (size_t)g * N_NODES * 4;
  const int K = KP, Nn = 256;
  int lane = t & 63, w = t >> 6;
  int mw = (w >> 1) * 64, nw = (w & 1) * 64;
  f32x4 acc[4][4] = {};
  for (int k0 = 0; k0 < K; k0 += 64){
    __syncthreads();
#pragma unroll
    for (int i = 0; i < 4; ++i){
      int c = i * 256 + w * 64 + lane;   // chunk id 0..1023, 16B each
      int row = c >> 3, slot = c & 7;
      int kk = ((slot ^ (row & 7))) * 8; // source-side XOR swizzle
      gll16(A  + (size_t)(m0 + row) * K + k0 + kk, As + (size_t)(i * 256 + w * 64) * 8);
      gll16(BT + (size_t)(n0 + row) * K + k0 + kk, Bs + (size_t)(i * 256 + w * 64) * 8);
    }
    __syncthreads();
#pragma unroll
    for (int ks = 0; ks < 2; ++ks){
      short8 af[4], bfr[4];
#pragma unroll
      for (int mi = 0; mi < 4; ++mi){
        int row = mw + mi * 16 + (lane & 15);
        int sl = (ks * 4 + (lane >> 4)) ^ (row & 7);
        af[mi] = *(const short8*)(As + (size_t)row * 64 + sl * 8);
      }
#pragma unroll
      for (int ni = 0; ni < 4; ++ni){
        int row = nw + ni * 16 + (lane & 15);
        int sl = (ks * 4 + (lane >> 4)) ^ (row & 7);
        bfr[ni] = *(const short8*)(Bs + (size_t)row * 64 + sl * 8);
      }
#pragma unroll
      for (int mi = 0; mi < 4; ++mi)
#pragma unroll
        for (int ni = 0; ni < 4; ++ni)
          acc[mi][ni] = __builtin_amdgcn_mfma_f32_16x16x32_bf16(af[mi], bfr[ni], acc[mi][ni], 0, 0, 0);
    }
  }
  int bf = *flag;
#pragma unroll
  for (int mi = 0; mi < 4; ++mi)
#pragma unroll
    for (int ni = 0; ni < 4; ++ni)
#pragma unroll
      for (int r = 0; r < 4; ++r){
        int row = m0 + mw + mi * 16 + (lane >> 4) * 4 + r;
        int col = n0 + nw + ni * 16 + (lane & 15);
        if (row < M) C[(size_t)row * Nn + col] = f2fp8(acc[mi][ni][r]);
      }
  // fused es/ed: this wave's cols = n0+nw..+63 = exactly one head; plain stores
  {
    int h = (n0 + nw) >> 6;
    float asv[4], adv[4];
#pragma unroll
    for (int ni = 0; ni < 4; ++ni){
      int col = n0 + nw + ni * 16 + (lane & 15);
      asv[ni] = ldp(as_, col, bf);
      adv[ni] = ldp(ad_, col, bf);
    }
#pragma unroll
    for (int mi = 0; mi < 4; ++mi)
#pragma unroll
      for (int r = 0; r < 4; ++r){
        float ps = 0.f, pd2 = 0.f;
#pragma unroll
        for (int ni = 0; ni < 4; ++ni){
          ps  += acc[mi][ni][r] * asv[ni];
          pd2 += acc[mi][ni][r] * adv[ni];
        }
#pragma unroll
        for (int m2 = 1; m2 < 16; m2 <<= 1){
          ps  += __shfl_xor(ps, m2);
          pd2 += __shfl_xor(pd2, m2);
        }
        int row = m0 + mw + mi * 16 + (lane >> 4) * 4 + r;
        if ((lane & 15) == 0 && row < M){
          es[(size_t)row * 4 + h] = ps;
          ed[(size_t)row * 4 + h] = pd2;
        }
      }
  }
}

// ---------------- small GEMM batched + fused es/ed (XOR-swizzled LDS) ----------------
__global__ __launch_bounds__(256) void gemm_small_kernel(
    const u16* A0, const u16* A1, const u16* A2,
    const u16* B0, const u16* B1, const u16* B2,
    u8* C0, u8* C1, u8* C2,
    const void* as0, const void* as1, const void* as2,
    const void* ad0, const void* ad1, const void* ad2,
    float* __restrict__ esB, float* __restrict__ edB,
    const int* __restrict__ flag, int M){
  int g = blockIdx.y;
  const u16* A  = g == 0 ? A0 : (g == 1 ? A1 : A2);
  const u16* BT = g == 0 ? B0 : (g == 1 ? B1 : B2);
  u8* C = g == 0 ? C0 : (g == 1 ? C1 : C2);
  const void* as_ = g == 0 ? as0 : (g == 1 ? as1 : as2);
  const void* ad_ = g == 0 ? ad0 : (g == 1 ? ad1 : ad2);
  float* es = esB + (size_t)g * N_NODES * 4;
  float* ed = edB + (size_t)g * N_NODES * 4;
  __shared__ alignas(16) u16 As[64 * 64];
  __shared__ alignas(16) u16 Bs[64 * 64];
  int t = threadIdx.x, lane = t & 63, w = t >> 6;
  int m0 = blockIdx.x * 64;
#pragma unroll
  for (int i = 0; i < 2; ++i){
    int c = i * 256 + w * 64 + lane;     // 512 chunks of 16B = 8KB tile
    int row = c >> 3, slot = c & 7;
    int kk = ((slot ^ (row & 7))) * 8;   // source-side XOR swizzle
    gll16(A  + (size_t)(m0 + row) * 64 + kk, As + (size_t)(i * 256 + w * 64) * 8);
    gll16(BT + (size_t)row * 64 + kk,        Bs + (size_t)(i * 256 + w * 64) * 8);
  }
  __syncthreads();
  f32x4 acc[4] = {};
  int mw = w * 16;
#pragma unroll
  for (int ks = 0; ks < 2; ++ks){
    int rowa = mw + (lane & 15);
    int sla = (ks * 4 + (lane >> 4)) ^ (rowa & 7);
    short8 af = *(const short8*)(As + (size_t)rowa * 64 + sla * 8);
#pragma unroll
    for (int ni = 0; ni < 4; ++ni){
      int rowb = ni * 16 + (lane & 15);
      int slb = (ks * 4 + (lane >> 4)) ^ (rowb & 7);
      short8 bv = *(const short8*)(Bs + (size_t)rowb * 64 + slb * 8);
      acc[ni] = __builtin_amdgcn_mfma_f32_16x16x32_bf16(af, bv, acc[ni], 0, 0, 0);
    }
  }
  int bf = *flag;
#pragma unroll
  for (int ni = 0; ni < 4; ++ni)
#pragma unroll
    for (int r = 0; r < 4; ++r){
      int row = m0 + mw + (lane >> 4) * 4 + r;
      int col = ni * 16 + (lane & 15);
      if (row < M) C[(size_t)row * 64 + col] = f2fp8(acc[ni][r]);
    }
  // fused es/ed: head = ni (16 cols per head, all 4 heads in-block) -> direct store
  {
    float asv[4], adv[4];
#pragma unroll
    for (int ni = 0; ni < 4; ++ni){
      int col = ni * 16 + (lane & 15);
      asv[ni] = ldp(as_, col, bf);
      adv[ni] = ldp(ad_, col, bf);
    }
#pragma unroll
    for (int r = 0; r < 4; ++r){
      float ps[4], pd2[4];
#pragma unroll
      for (int ni = 0; ni < 4; ++ni){ ps[ni] = acc[ni][r] * asv[ni]; pd2[ni] = acc[ni][r] * adv[ni]; }
#pragma unroll
      for (int m2 = 1; m2 < 16; m2 <<= 1)
#pragma unroll
        for (int ni = 0; ni < 4; ++ni){
          ps[ni]  += __shfl_xor(ps[ni], m2);
          pd2[ni] += __shfl_xor(pd2[ni], m2);
        }
      int row = m0 + mw + (lane >> 4) * 4 + r;
      if ((lane & 15) == 0 && row < M){
#pragma unroll
        for (int ni = 0; ni < 4; ++ni){
          es[(size_t)row * 4 + ni] = ps[ni];
          ed[(size_t)row * 4 + ni] = pd2[ni];
        }
      }
    }
  }
}

// ---------------- GAT aggregate from fp8 z (verbatim round-0 known-best body) --------
// 6 structural rewrites (r1-r6) all landed >= this body's 57.5us floor; keep verbatim.
template<int DT, bool RELU, bool BF16OUT, int PIPE>   // DT = channels = bytes/row
__global__ __launch_bounds__(256) void gat_agg5_kernel(
    const u8* z0, const u8* z1, const u8* z2,
    const float* __restrict__ esB, const float* __restrict__ edB,
    const int2* __restrict__ metaB,
    const int* e0p, const int* e1p, const int* e2p,
    const void* b0, const void* b1, const void* b2,
    void* o0, void* o1, void* o2,
    const int* __restrict__ flag){
  int g = blockIdx.y;
  const u8* z = g == 0 ? z0 : (g == 1 ? z1 : z2);
  const int* esrc = g == 0 ? e0p : (g == 1 ? e1p : e2p);
  const void* bias = g == 0 ? b0 : (g == 1 ? b1 : b2);
  void* out = g == 0 ? o0 : (g == 1 ? o1 : o2);
  const float* es = esB + (size_t)g * N_NODES * 4;
  const float* ed = edB + (size_t)g * N_NODES * 4;
  const int2* meta = metaB + (size_t)g * MP;
  int bf = *flag;

  int d = (blockIdx.x * 256 + threadIdx.x) >> 6;
  int lane = threadIdx.x & 63;
  if (d >= N_NODES) return;
  constexpr int LPG = DT / 8;        // lanes per edge-group: 32 (DT256) / 8 (DT64)
  constexpr int G   = 64 / LPG;      // groups: 2 / 8
  constexpr int HD  = DT / 4;        // channels per head == output width: 64 / 16
  int grp = lane / LPG;
  int li  = lane % LPG;
  int c0  = li * 8;                  // byte offset of this lane's 8 channels
  int h   = c0 / HD;

  int2 md = meta[d];
  int deg = md.y;
  const int* ep = esrc + md.x;
  float edh = ed[(unsigned)d * 4 + h];

  float acc[8] = {0,0,0,0,0,0,0,0};
  float sacc = 0.f;

  int steps = (deg + PIPE * G - 1) / (PIPE * G);
  for (int tb = 0; tb < steps; ++tb){
    int e0 = tb * PIPE * G + grp;
    int s[PIPE]; float q[PIPE]; uv2 v[PIPE]; bool val[PIPE];
#pragma unroll
    for (int i = 0; i < PIPE; ++i){
      int e = e0 + i * G;
      val[i] = e < deg;
      int sl = ep[e];                // over-read stays within slack region
      s[i] = val[i] ? sl : 0;
    }
#pragma unroll
    for (int i = 0; i < PIPE; ++i) q[i] = es[(unsigned)s[i] * 4 + h];
#pragma unroll
    for (int i = 0; i < PIPE; ++i) v[i] = *(const uv2*)(z + (unsigned)s[i] * DT + c0);
#pragma unroll
    for (int i = 0; i < PIPE; ++i){
      float p = val[i] ? __expf(lrelu(q[i] + edh)) : 0.f;
      sacc += p;
      f32x2 a0 = fp8pair<false>(v[i][0]), a1 = fp8pair<true>(v[i][0]);
      f32x2 a2 = fp8pair<false>(v[i][1]), a3 = fp8pair<true>(v[i][1]);
      acc[0] = fmaf(p, a0.x, acc[0]); acc[1] = fmaf(p, a0.y, acc[1]);
      acc[2] = fmaf(p, a1.x, acc[2]); acc[3] = fmaf(p, a1.y, acc[3]);
      acc[4] = fmaf(p, a2.x, acc[4]); acc[5] = fmaf(p, a2.y, acc[5]);
      acc[6] = fmaf(p, a3.x, acc[6]); acc[7] = fmaf(p, a3.y, acc[7]);
    }
  }

  // sum over edge-groups (lanes with same li share channel+head)
#pragma unroll
  for (int m = LPG; m < 64; m <<= 1){
    sacc += __shfl_xor(sacc, m);
#pragma unroll
    for (int j = 0; j < 8; ++j) acc[j] += __shfl_xor(acc[j], m);
  }
  float inv = 1.f / (sacc + 1e-16f);
  float v8[8];
#pragma unroll
  for (int j = 0; j < 8; ++j) v8[j] = acc[j] * inv;
  // mean over heads: lanes li, li^(HD/8), ... hold same dd different heads
#pragma unroll
  for (int m = HD / 8; m < LPG; m <<= 1)
#pragma unroll
    for (int j = 0; j < 8; ++j) v8[j] += __shfl_xor(v8[j], m);

  if (lane < HD / 8){
    if constexpr (BF16OUT){
      short8 ov;
#pragma unroll
      for (int j = 0; j < 8; ++j){
        float o = v8[j] * 0.25f + ldp(bias, lane * 8 + j, bf);
        if (RELU) o = fmaxf(o, 0.f);
        ov[j] = (short)f2b(o);
      }
      *(short8*)((u16*)out + (size_t)d * HD + lane * 8) = ov;
    } else {
      float o[8];
#pragma unroll
      for (int j = 0; j < 8; ++j){
        o[j] = v8[j] * 0.25f + ldp(bias, lane * 8 + j, bf);
        if (RELU) o[j] = fmaxf(o[j], 0.f);
      }
      float* op = (float*)out + (size_t)d * HD + lane * 8;
      *(float4*)op = make_float4(o[0], o[1], o[2], o[3]);
      *(float4*)(op + 4) = make_float4(o[4], o[5], o[6], o[7]);
    }
  }
}

// ---------------- final: branch attention + combine + log_softmax ----------------
__global__ __launch_bounds__(256) void final_combine_kernel(
    const float* __restrict__ h1, const float* __restrict__ h2, const float* __restrict__ h3,
    const void* l1w, const void* l1b, const void* l2w, const void* l2b,
    const void* l3w, const void* l3b, const void* aggw,
    void* __restrict__ outv, int n, const int* __restrict__ flag){
  __shared__ float Lw[3][16][16];
  __shared__ float Lb[3][16];
  __shared__ float Ag[16];
  int t = threadIdx.x;
  int bf = *flag;
  {
    const void* ws[3] = { l1w, l2w, l3w };
    for (int g = 0; g < 3; ++g) Lw[g][t / 16][t % 16] = ldp(ws[g], t, bf);
    if (t < 16){
      Lb[0][t] = ldp(l1b, t, bf); Lb[1][t] = ldp(l2b, t, bf); Lb[2][t] = ldp(l3b, t, bf);
      Ag[t] = ldp(aggw, t, bf);
    }
  }
  __syncthreads();
  int node = blockIdx.x * 256 + t;
  if (node >= n) return;
  const float* hp[3] = { h1, h2, h3 };
  float hv[3][16];
  float a[3];
  for (int g = 0; g < 3; ++g){
    const float4* h4 = (const float4*)(hp[g] + (size_t)node * 16);
#pragma unroll
    for (int q = 0; q < 4; ++q){
      float4 f = h4[q];
      hv[g][q * 4 + 0] = f.x; hv[g][q * 4 + 1] = f.y;
      hv[g][q * 4 + 2] = f.z; hv[g][q * 4 + 3] = f.w;
    }
    float dot = 0.f;
#pragma unroll
    for (int j = 0; j < 16; ++j){
      float acc2 = Lb[g][j];
#pragma unroll
      for (int i = 0; i < 16; ++i) acc2 += hv[g][i] * Lw[g][i][j];
      dot += ftanh(acc2) * Ag[j];
    }
    a[g] = dot;
  }
  float am = fmaxf(a[0], fmaxf(a[1], a[2]));
  float e0 = __expf(a[0] - am), e1 = __expf(a[1] - am), e2 = __expf(a[2] - am);
  float einv = 1.f / (e0 + e1 + e2);
  float w0 = e0 * einv, w1 = e1 * einv, w2 = e2 * einv;
  float hh[16];
  float hmax = -INFINITY;
#pragma unroll
  for (int i = 0; i < 16; ++i){
    hh[i] = w0 * hv[0][i] + w1 * hv[1][i] + w2 * hv[2][i];
    hmax = fmaxf(hmax, hh[i]);
  }
  float se = 0.f;
#pragma unroll
  for (int i = 0; i < 16; ++i) se += __expf(hh[i] - hmax);
  float ls = hmax + logf(se);
#pragma unroll
  for (int i = 0; i < 16; ++i){
    float o = hh[i] - ls;
    if (bf) ((__hip_bfloat16*)outv)[(size_t)node * 16 + i] = __float2bfloat16(o);
    else    ((float*)outv)[(size_t)node * 16 + i] = o;
  }
}

// ---------------- host ----------------
extern "C" void kernel_launch(void* const* d_in, const int* in_sizes, int n_in,
                              void* d_out, int out_size, void* d_ws, size_t ws_size,
                              hipStream_t stream){
  const void* x = d_in[0];
  const int* ei[3] = { (const int*)d_in[1], (const int*)d_in[2], (const int*)d_in[3] };
  int E[3] = { in_sizes[1] / 2, in_sizes[2] / 2, in_sizes[3] / 2 };
  int Emax = E[0] > E[1] ? E[0] : E[1]; if (E[2] > Emax) Emax = E[2];
  int EB = (Emax + CHA - 1) / CHA;
  int S[3];
  for (int g = 0; g < 3; ++g){
    long s = ((long)E[g] * 27 / 20) / NBUCK + 64;
    s &= ~63L; if (s > 8192) s = 8192;
    S[g] = (int)s;
  }
  const void *W[6], *as_[6], *ad_[6], *bb[6];
  for (int j = 0; j < 6; ++j){
    W[j]   = d_in[4 + 4 * j];
    as_[j] = d_in[5 + 4 * j];
    ad_[j] = d_in[6 + 4 * j];
    bb[j]  = d_in[7 + 4 * j];
  }
  const void* l1w = d_in[28]; const void* l1b = d_in[29];
  const void* l2w = d_in[30]; const void* l2b = d_in[31];
  const void* l3w = d_in[32]; const void* l3b = d_in[33];
  const void* agg = d_in[34];

  // ---- workspace carve ----
  char* p = (char*)d_ws;
  auto alloc = [&](size_t bytes) -> void* {
    void* r = (void*)p;
    p += (bytes + 255) & ~(size_t)255;
    return r;
  };
  int* dflag = (int*)alloc(256);
  u16* xp = (u16*)alloc((size_t)MP * KP * 2);           // padded x, bf16 (20.6 MB)
  u16* hmid[3]; for (int g = 0; g < 3; ++g) hmid[g] = xp + (size_t)g * MP * 64;       // alias
  u16* wtb[3]; for (int g = 0; g < 3; ++g) wtb[g] = (u16*)alloc((size_t)256 * KP * 2);
  u16* wts[3]; for (int g = 0; g < 3; ++g) wts[g] = (u16*)alloc((size_t)64 * 64 * 2);
  u8* zf[3];   for (int g = 0; g < 3; ++g) zf[g]  = (u8*)alloc((size_t)N_NODES * 256 + 256);
  float* hbr[3]; for (int g = 0; g < 3; ++g) hbr[g] = (float*)alloc((size_t)N_NODES * 16 * 4);
  float* esB = (float*)alloc((size_t)3 * N_NODES * 4 * 4);
  float* edB = (float*)alloc((size_t)3 * N_NODES * 4 * 4);
  int* bucketCur = (int*)alloc((size_t)3 * NBUCK * 4);
  int2* metaB    = (int2*)alloc((size_t)3 * MP * 8);
  int* esrc[3];
  for (int g = 0; g < 3; ++g) esrc[g] = (int*)alloc(((size_t)NBUCK * S[g] + 256) * 4);
  unsigned* pairs[3];
  for (int g = 0; g < 3; ++g) pairs[g] = (unsigned*)alloc(((size_t)NBUCK * S[g] + 256) * 4);

  const int* s0 = ei[0];          const int* s1 = ei[1];          const int* s2 = ei[2];
  const int* d0 = ei[0] + E[0];   const int* d1 = ei[1] + E[1];   const int* d2 = ei[2] + E[2];

  (void)hipMemsetAsync(bucketCur, 0, (size_t)3 * NBUCK * 4, stream);
  prep_kernel<<<dim3((MP * 64 + PB - 1) / PB, 3), PB, 0, stream>>>(
      x, xp, W[0], W[2], W[4], W[1], W[3], W[5],
      wtb[0], wtb[1], wtb[2], wts[0], wts[1], wts[2],
      s0, s1, s2, d0, d1, d2, E[0], E[1], E[2], S[0], S[1], S[2], EB,
      bucketCur, pairs[0], pairs[1], pairs[2], dflag);

  const int convGrid = (N_NODES + 3) / 4;   // 4 waves/block, wave per dst

  // layer 1 GEMM (z=0, 20 supergroups x 48 blocks) + fused csr finalize (z=1)
  gemm_big_kernel<<<dim3(20 * 48, 1, 2), 256, 0, stream>>>(
      xp, wtb[0], wtb[1], wtb[2], zf[0], zf[1], zf[2],
      as_[0], as_[2], as_[4], ad_[0], ad_[2], ad_[4], esB, edB, dflag, N_NODES,
      pairs[0], pairs[1], pairs[2], S[0], S[1], S[2], bucketCur,
      esrc[0], esrc[1], esrc[2], metaB);
  gat_agg5_kernel<256, true, true, 6><<<dim3(convGrid, 3), 256, 0, stream>>>(
      zf[0], zf[1], zf[2], esB, edB, metaB, esrc[0], esrc[1], esrc[2],
      bb[0], bb[2], bb[4], (void*)hmid[0], (void*)hmid[1], (void*)hmid[2], dflag);

  // layer 2: 64 -> 16, H=4 (DT=64), no relu, fp32 out into hbr
  gemm_small_kernel<<<dim3(MP / 64, 3), 256, 0, stream>>>(
      hmid[0], hmid[1], hmid[2], wts[0], wts[1], wts[2], zf[0], zf[1], zf[2],
      as_[1], as_[3], as_[5], ad_[1], ad_[3], ad_[5], esB, edB, dflag, N_NODES);
  gat_agg5_kernel<64, false, false, 4><<<dim3(convGrid, 3), 256, 0, stream>>>(
      zf[0], zf[1], zf[2], esB, edB, metaB, esrc[0], esrc[1], esrc[2],
      bb[1], bb[3], bb[5], (void*)hbr[0], (void*)hbr[1], (void*)hbr[2], dflag);

  final_combine_kernel<<<(N_NODES + 255) / 256, 256, 0, stream>>>(
      hbr[0], hbr[1], hbr[2], l1w, l1b, l2w, l2b, l3w, l3b, agg,
      d_out, N_NODES, dflag);
}